// Round 9
// baseline (559.246 us; speedup 1.0000x reference)
//
#include <hip/hip_runtime.h>
#include <math.h>

typedef __attribute__((ext_vector_type(8))) short short8;
typedef __attribute__((ext_vector_type(4))) float f32x4;
typedef __attribute__((ext_vector_type(4))) unsigned short us4;
typedef __attribute__((ext_vector_type(4))) float fl4;

#define B_ 2
#define S_ 2048
#define H_ 16
#define D_ 128
#define HID 2048

__device__ __forceinline__ unsigned short f2bf(float f){
  unsigned u = __builtin_bit_cast(unsigned, f);
  u += 0x7fffu + ((u >> 16) & 1u);
  return (unsigned short)(u >> 16);
}
__device__ __forceinline__ float bf2f(unsigned short u){
  unsigned x = ((unsigned)u) << 16;
  return __builtin_bit_cast(float, x);
}
__device__ __forceinline__ int cvtpk(float lo, float hi){
  int r; asm("v_cvt_pk_bf16_f32 %0, %1, %2" : "=v"(r) : "v"(lo), "v"(hi)); return r;
}

// async global -> LDS, 16 bytes per lane (dest linear: base + lane*16)
__device__ __forceinline__ void g2lds16(const unsigned short* g, unsigned short* l){
  __builtin_amdgcn_global_load_lds(
      (const __attribute__((address_space(1))) unsigned int*)g,
      (__attribute__((address_space(3))) unsigned int*)l, 16, 0, 0);
}

// ---------- f32 -> bf16 convert ----------
__global__ void cvt_k(const float* __restrict__ src, unsigned short* __restrict__ dst){
  int i = (blockIdx.x * 256 + threadIdx.x) * 4;
  fl4 v = *(const fl4*)(src + i);
  us4 o;
  #pragma unroll
  for (int t = 0; t < 4; t++) o[t] = f2bf(v[t]);
  *(us4*)(dst + i) = o;
}

// ---------- cos/sin tables ----------
__global__ void tab_k(const float* __restrict__ freqs, float* __restrict__ ctab,
                      float* __restrict__ stab){
  int i = blockIdx.x * 256 + threadIdx.x;
  float f = freqs[i];
  ctab[i] = cosf(f);
  stab[i] = sinf(f);
}

// ================= 256x256 8-phase GEMM (T2+T3+T4+T5) — unchanged R8 ========
#define PHEND_VM  do { asm volatile("s_waitcnt vmcnt(6)" ::: "memory"); \
  __builtin_amdgcn_sched_barrier(0); __builtin_amdgcn_s_barrier(); } while(0)
#define PHEND     do { \
  __builtin_amdgcn_sched_barrier(0); __builtin_amdgcn_s_barrier(); } while(0)
#define PREBAR    __builtin_amdgcn_s_barrier()

#define RD_A(slotb, half) do { _Pragma("unroll") \
  for (int i = 0; i < 4; i++){ _Pragma("unroll") \
    for (int ks = 0; ks < 2; ks++) \
      a[i][ks] = *(const short8*)(L + (slotb) + (half)*8192 + abase + i*2048 + kg[ks]); } } while(0)

#define RD_B(slotb, half) do { _Pragma("unroll") \
  for (int n = 0; n < 2; n++){ _Pragma("unroll") \
    for (int ks = 0; ks < 2; ks++) \
      b[(half)*2+n][ks] = *(const short8*)(L + (slotb) + 16384 + (half)*8192 + bbase + n*4096 + kg[ks]); } } while(0)

#define MMQ(X, Y) do { __builtin_amdgcn_s_setprio(1); _Pragma("unroll") \
  for (int i = 0; i < 4; i++){ _Pragma("unroll") \
    for (int n = 0; n < 2; n++){ _Pragma("unroll") \
      for (int ks = 0; ks < 2; ks++) \
        acc[(X)*4+i][(Y)*2+n] = __builtin_amdgcn_mfma_f32_16x16x32_bf16( \
            a[i][ks], b[(Y)*2+n][ks], acc[(X)*4+i][(Y)*2+n], 0, 0, 0); } } \
  __builtin_amdgcn_s_setprio(0); } while(0)

template<int EPI>   // 1: QKV (z selects Wq/Wk/Wv; z=2 writes V^T), 0: f32 out
__global__ __launch_bounds__(512, 2) void gemm8_k(
    const unsigned short* __restrict__ A,
    const unsigned short* __restrict__ W0,
    const unsigned short* __restrict__ W1,
    const unsigned short* __restrict__ W2,
    unsigned short* __restrict__ O0,
    unsigned short* __restrict__ O1,
    unsigned short* __restrict__ O2,
    float* __restrict__ Of)
{
  __shared__ __align__(16) unsigned short L[2 * 4 * 8192];   // 128 KiB
  const int tid = threadIdx.x;
  const int l = tid & 63, lg = l >> 4, lr = l & 15;
  const int w = tid >> 6, wm = w >> 2, wn = w & 3;
  const int m0 = blockIdx.x * 256, n0 = blockIdx.y * 256;
  const int z = (EPI == 1) ? blockIdx.z : 0;
  const unsigned short* Bop = (EPI == 1) ? (z == 0 ? W0 : (z == 1 ? W1 : W2)) : W0;

  f32x4 acc[8][4];
  #pragma unroll
  for (int i = 0; i < 8; i++)
    #pragma unroll
    for (int j = 0; j < 4; j++)
      acc[i][j] = f32x4{0.f, 0.f, 0.f, 0.f};

  const int gsw = (((tid & 7) ^ ((tid >> 3) & 7)) * 8);
  const unsigned short* gA = A   + (size_t)(m0 + (tid >> 3)) * HID + gsw;
  const unsigned short* gB = Bop + (size_t)(n0 + (tid >> 3)) * HID + gsw;
  const size_t HIN = (size_t)64  * HID;
  const size_t HB  = (size_t)128 * HID;

  const int abase = (wm * 16 + lr) * 64;
  const int bbase = (wn * 16 + lr) * 64;
  int kg[2];
  kg[0] = ((lg)     ^ (lr & 7)) * 8;
  kg[1] = ((4 + lg) ^ (lr & 7)) * 8;

  #define STG(gsrc, tile, ldst) do { \
    const unsigned short* _s = (gsrc) + (size_t)(tile) * 64; \
    g2lds16(_s,       (ldst) + tid * 8); \
    g2lds16(_s + HIN, (ldst) + 4096 + tid * 8); } while(0)

  short8 a[4][2], b[4][2];

  STG(gA, 0, L);
  STG(gA + HB, 0, L + 8192);
  STG(gB, 0, L + 16384);
  STG(gB + HB, 0, L + 24576);
  asm volatile("s_waitcnt vmcnt(0)" ::: "memory");
  __builtin_amdgcn_sched_barrier(0);
  __builtin_amdgcn_s_barrier();
  STG(gA, 1, L + 32768);

  for (int it = 0; it < 16; ++it){
    const int t1 = 2 * it + 1, t2 = 2 * it + 2, t3 = 2 * it + 3;
    RD_A(0, 0); RD_B(0, 0);
    STG(gB, t1, L + 32768 + 16384);
    PREBAR; MMQ(0, 0); PHEND_VM;
    RD_B(0, 1);
    STG(gB + HB, t1, L + 32768 + 24576);
    PREBAR; MMQ(0, 1); PHEND_VM;
    RD_A(0, 1);
    STG(gA + HB, t1, L + 32768 + 8192);
    PREBAR; MMQ(1, 0); PHEND;
    STG(gA, t2, L);
    PREBAR; MMQ(1, 1); PHEND_VM;
    RD_A(32768, 0); RD_B(32768, 0);
    STG(gB, t2, L + 16384);
    PREBAR; MMQ(0, 0); PHEND_VM;
    RD_B(32768, 1);
    STG(gB + HB, t2, L + 24576);
    PREBAR; MMQ(0, 1); PHEND_VM;
    RD_A(32768, 1);
    STG(gA + HB, t2, L + 8192);
    PREBAR; MMQ(1, 0); PHEND;
    STG(gA, t3, L + 32768);
    PREBAR; MMQ(1, 1); PHEND_VM;
  }
  #undef STG

  #pragma unroll
  for (int mf = 0; mf < 8; mf++)
    #pragma unroll
    for (int nf = 0; nf < 4; nf++){
      const int j = n0 + nf * 64 + wn * 16 + lr;
      const int i0 = m0 + mf * 32 + wm * 16 + lg * 4;
      if (EPI == 0){
        #pragma unroll
        for (int r = 0; r < 4; r++)
          Of[(size_t)(i0 + r) * HID + j] = acc[mf][nf][r];
      } else if (z == 2){
        const int b = i0 >> 11, s = i0 & 2047, h = j >> 7, d = j & 127;
        us4 v;
        #pragma unroll
        for (int r = 0; r < 4; r++) v[r] = f2bf(acc[mf][nf][r]);
        *(us4*)(O2 + ((size_t)(b * H_ + h) * D_ + d) * S_ + s) = v;
      } else {
        unsigned short* O = z ? O1 : O0;
        const int h = j >> 7, d = j & 127;
        #pragma unroll
        for (int r = 0; r < 4; r++){
          const int i = i0 + r;
          const int b = i >> 11, s = i & 2047;
          O[((size_t)(b * H_ + h) * S_ + s) * D_ + d] = f2bf(acc[mf][nf][r]);
        }
      }
    }
}

// ---------- in-place RoPE on Q and K ----------
__global__ void rope_k(unsigned short* __restrict__ Q, unsigned short* __restrict__ K,
                       const float* __restrict__ ctab, const float* __restrict__ stab){
  int idx = blockIdx.x * 256 + threadIdx.x;
  unsigned short* P = (idx >= (1 << 20)) ? K : Q;
  int e  = idx & ((1 << 20) - 1);
  int g  = e & 15;
  int s  = (e >> 4) & 2047;
  int bh = e >> 15;
  int d0 = g * 4;
  size_t base = ((size_t)bh * S_ + s) * D_;
  us4 qa = *(us4*)(P + base + d0);
  us4 qb = *(us4*)(P + base + d0 + 64);
  fl4 ca = *(const fl4*)(ctab + s * D_ + d0);
  fl4 sa = *(const fl4*)(stab + s * D_ + d0);
  fl4 cb = *(const fl4*)(ctab + s * D_ + d0 + 64);
  fl4 sb = *(const fl4*)(stab + s * D_ + d0 + 64);
  us4 oa, ob;
  #pragma unroll
  for (int t = 0; t < 4; t++){
    float xa = bf2f(qa[t]), xb = bf2f(qb[t]);
    oa[t] = f2bf(xa * ca[t] - xb * sa[t]);
    ob[t] = f2bf(xb * cb[t] + xa * sb[t]);
  }
  *(us4*)(P + base + d0)      = oa;
  *(us4*)(P + base + d0 + 64) = ob;
}

// ---------- flash attention: KVBLK=32 dbuf (32KB LDS -> 4 blocks/CU) ----------
__global__ __launch_bounds__(256) void attn_k(
    const unsigned short* __restrict__ Q,
    const unsigned short* __restrict__ Kg,
    const unsigned short* __restrict__ Vt,
    const float* __restrict__ mask,
    const float* __restrict__ alibi,
    unsigned short* __restrict__ Ctx)
{
  __shared__ __align__(16) unsigned short Kl[2][32 * 128];  // 16 KB
  __shared__ __align__(16) unsigned short Vl[2][128 * 32];  // 16 KB
  const int tid = threadIdx.x;
  const int l = tid & 63, lg = l >> 4, lr = l & 15;
  const int w = tid >> 6;
  const int bh = blockIdx.y, b = bh >> 4, h = bh & 15;
  const int q0 = blockIdx.x * 64 + w * 16;
  const size_t hb = (size_t)bh * S_ * D_;
  const float* mrow = mask + (size_t)(q0 + lr) * S_;
  const float* al = alibi + h * S_;
  const int sidx = (l & 48) + ((l & 48) >> 2);
  const float SCL2E = 0.08838834764831845f * 1.4426950408889634f;
  const float L2E = 1.4426950408889634f;

  // staging: pre-swizzled global source, linear LDS dest.
  // K tile [32][128]: 16 granules/row, swz ^row&7 (rows via 2 g2lds of 16 rows)
  const unsigned short* gK = Kg + hb + (size_t)(tid >> 4) * D_
                             + (((tid & 15) ^ ((tid >> 4) & 7)) * 8);
  // V^T tile [128][32]: 4 granules/row, swz ^row&3 (rows via 2 g2lds of 64 rows)
  const unsigned short* gV = Vt + hb + (size_t)(tid >> 2) * S_
                             + (((tid & 3) ^ ((tid >> 2) & 3)) * 8);

  #define ASTAGE(buf, kv)  do {                                            \
    g2lds16(gK + (size_t)((kv))      * D_, Kl[buf] + tid * 8);             \
    g2lds16(gK + (size_t)((kv) + 16) * D_, Kl[buf] + 2048 + tid * 8);      \
    g2lds16(gV + (kv),                     Vl[buf] + tid * 8);             \
    g2lds16(gV + 64 * S_ + (kv),           Vl[buf] + 2048 + tid * 8);      \
  } while (0)

  int koff[4];
  #pragma unroll
  for (int c = 0; c < 4; c++) koff[c] = ((c * 4 + lg) ^ (lr & 7)) * 8;
  const int vo = (lg ^ (lr & 3)) * 8;

  short8 qf[4];
  #pragma unroll
  for (int c = 0; c < 4; c++)
    qf[c] = *(const short8*)(Q + hb + (size_t)(q0 + lr) * D_ + c * 32 + lg * 8);

  f32x4 acc[8];
  #pragma unroll
  for (int c = 0; c < 8; c++) acc[c] = f32x4{0.f, 0.f, 0.f, 0.f};
  float mr = -1e30f, lsum = 0.f;

  ASTAGE(0, 0);
  __syncthreads();
  int cur = 0;

  for (int t = 0; t < 64; t++){
    const int kv0 = t * 32;
    if (t < 63) ASTAGE(cur ^ 1, kv0 + 32);

    fl4 mk[2], aa[2];
    #pragma unroll
    for (int g = 0; g < 2; g++){
      mk[g] = *(const fl4*)(mrow + kv0 + g * 16 + 4 * lg);
      aa[g] = *(const fl4*)(al  + kv0 + g * 16 + 4 * lg);
    }

    // S^T[k][q] = K · Q^T, 2 k-groups of 16
    f32x4 sg[2];
    #pragma unroll
    for (int g = 0; g < 2; g++) sg[g] = f32x4{0.f, 0.f, 0.f, 0.f};
    #pragma unroll
    for (int g = 0; g < 2; g++){
      const int row = g * 16 + lr;
      #pragma unroll
      for (int c = 0; c < 4; c++){
        short8 kf = *(const short8*)(Kl[cur] + row * 128 + koff[c]);
        sg[g] = __builtin_amdgcn_mfma_f32_16x16x32_bf16(kf, qf[c], sg[g], 0, 0, 0);
      }
    }

    float x[2][4];
    #pragma unroll
    for (int g = 0; g < 2; g++)
      #pragma unroll
      for (int r = 0; r < 4; r++)
        x[g][r] = fmaf(sg[g][r], SCL2E, (mk[g][r] + aa[g][r]) * L2E);

    float mx = -1e30f;
    #pragma unroll
    for (int g = 0; g < 2; g++)
      #pragma unroll
      for (int r = 0; r < 4; r++) mx = fmaxf(mx, x[g][r]);

    float p[2][4], ps = 0.f;
    if (__all(mx <= mr + 8.f)){
      #pragma unroll
      for (int g = 0; g < 2; g++)
        #pragma unroll
        for (int r = 0; r < 4; r++){
          p[g][r] = exp2f(x[g][r] - mr);
          ps += p[g][r];
        }
      ps += __shfl_xor(ps, 16);
      ps += __shfl_xor(ps, 32);
      lsum += ps;
    } else {
      mx = fmaxf(mx, __shfl_xor(mx, 16));
      mx = fmaxf(mx, __shfl_xor(mx, 32));
      float mnew = fmaxf(mr, mx);
      float alpha = exp2f(mr - mnew);
      #pragma unroll
      for (int g = 0; g < 2; g++)
        #pragma unroll
        for (int r = 0; r < 4; r++){
          p[g][r] = exp2f(x[g][r] - mnew);
          ps += p[g][r];
        }
      ps += __shfl_xor(ps, 16);
      ps += __shfl_xor(ps, 32);
      lsum = lsum * alpha + ps;
      mr = mnew;
      float ar[4];
      #pragma unroll
      for (int r = 0; r < 4; r++) ar[r] = __shfl(alpha, sidx + r);
      #pragma unroll
      for (int c = 0; c < 8; c++)
        #pragma unroll
        for (int r = 0; r < 4; r++) acc[c][r] *= ar[r];
    }

    int pk[4];
    #pragma unroll
    for (int r = 0; r < 4; r++)
      pk[r] = cvtpk(p[0][r], p[1][r]);

    // redistribute: lane needs P[q=lr][k = 8*lg + j]
    const int srcb = lr + ((lg & 1) << 5);
    short8 af;
    #pragma unroll
    for (int j = 0; j < 8; j++){
      int w0 = __shfl(pk[j & 3], srcb + ((j >> 2) << 4));
      af[j] = (short)((l & 32) ? ((unsigned)w0 >> 16) : ((unsigned)w0 & 0xffffu));
    }

    // PV: acc[c] += P(16x32) · V^T rows d (one MFMA per d-chunk)
    #pragma unroll
    for (int c = 0; c < 8; c++){
      short8 vf = *(const short8*)(Vl[cur] + (c * 16 + lr) * 32 + vo);
      acc[c] = __builtin_amdgcn_mfma_f32_16x16x32_bf16(af, vf, acc[c], 0, 0, 0);
    }

    __syncthreads();
    cur ^= 1;
  }
  #undef ASTAGE

  float inv = 1.f / lsum;
  float ir[4];
  #pragma unroll
  for (int r = 0; r < 4; r++) ir[r] = __shfl(inv, sidx + r);
  #pragma unroll
  for (int r = 0; r < 4; r++){
    const int qg = q0 + 4 * lg + r;
    const size_t ob = ((size_t)(b * S_ + qg) * H_ + h) * D_;
    #pragma unroll
    for (int c = 0; c < 8; c++)
      Ctx[ob + c * 16 + lr] = f2bf(acc[c][r] * ir[r]);
  }
}

extern "C" void kernel_launch(void* const* d_in, const int* in_sizes, int n_in,
                              void* d_out, int out_size, void* d_ws, size_t ws_size,
                              hipStream_t stream){
  const float* x     = (const float*)d_in[0];
  const float* mask  = (const float*)d_in[1];
  const float* alibi = (const float*)d_in[2];
  const float* freqs = (const float*)d_in[3];
  const float* Wq    = (const float*)d_in[4];
  const float* Wk    = (const float*)d_in[5];
  const float* Wv    = (const float*)d_in[6];
  const float* Wo    = (const float*)d_in[7];
  float* out = (float*)d_out;

  unsigned short* ws  = (unsigned short*)d_ws;
  unsigned short* xb  = ws;
  unsigned short* wqb = ws + 8388608;
  unsigned short* wkb = ws + 12582912;
  unsigned short* wvb = ws + 16777216;
  unsigned short* wob = ws + 20971520;
  unsigned short* Qb  = ws + 25165824;
  unsigned short* Kb  = ws + 33554432;
  unsigned short* Vb  = ws + 41943040;         // V^T [B,H,D,S]
  unsigned short* ctx = xb;
  float* ctab = (float*)(ws + 50331648);
  float* stab = ctab + 262144;

  cvt_k<<<8192, 256, 0, stream>>>(x,  xb);
  cvt_k<<<4096, 256, 0, stream>>>(Wq, wqb);
  cvt_k<<<4096, 256, 0, stream>>>(Wk, wkb);
  cvt_k<<<4096, 256, 0, stream>>>(Wv, wvb);
  cvt_k<<<4096, 256, 0, stream>>>(Wo, wob);
  tab_k<<<1024, 256, 0, stream>>>(freqs, ctab, stab);

  gemm8_k<1><<<dim3(16, 8, 3), 512, 0, stream>>>(xb, wqb, wkb, wvb,
                                                 Qb, Kb, Vb, nullptr);
  rope_k<<<8192, 256, 0, stream>>>(Qb, Kb, ctab, stab);
  attn_k<<<dim3(32, 32), 256, 0, stream>>>(Qb, Kb, Vb, mask, alibi, ctx);
  gemm8_k<0><<<dim3(16, 8, 1), 512, 0, stream>>>(ctx, wob, nullptr, nullptr,
                                                 nullptr, nullptr, nullptr, out);
}

// Round 10
// 498.807 us; speedup vs baseline: 1.1212x; 1.1212x over previous
//
#include <hip/hip_runtime.h>
#include <math.h>

typedef __attribute__((ext_vector_type(8))) short short8;
typedef __attribute__((ext_vector_type(4))) float f32x4;
typedef __attribute__((ext_vector_type(4))) unsigned short us4;
typedef __attribute__((ext_vector_type(4))) float fl4;

#define B_ 2
#define S_ 2048
#define H_ 16
#define D_ 128
#define HID 2048

__device__ __forceinline__ unsigned short f2bf(float f){
  unsigned u = __builtin_bit_cast(unsigned, f);
  u += 0x7fffu + ((u >> 16) & 1u);
  return (unsigned short)(u >> 16);
}
__device__ __forceinline__ float bf2f(unsigned short u){
  unsigned x = ((unsigned)u) << 16;
  return __builtin_bit_cast(float, x);
}
__device__ __forceinline__ int cvtpk(float lo, float hi){
  int r; asm("v_cvt_pk_bf16_f32 %0, %1, %2" : "=v"(r) : "v"(lo), "v"(hi)); return r;
}

// async global -> LDS, 16 bytes per lane (dest linear: base + lane*16)
__device__ __forceinline__ void g2lds16(const unsigned short* g, unsigned short* l){
  __builtin_amdgcn_global_load_lds(
      (const __attribute__((address_space(1))) unsigned int*)g,
      (__attribute__((address_space(3))) unsigned int*)l, 16, 0, 0);
}

// ---------- f32 -> bf16 convert ----------
__global__ void cvt_k(const float* __restrict__ src, unsigned short* __restrict__ dst){
  int i = (blockIdx.x * 256 + threadIdx.x) * 4;
  fl4 v = *(const fl4*)(src + i);
  us4 o;
  #pragma unroll
  for (int t = 0; t < 4; t++) o[t] = f2bf(v[t]);
  *(us4*)(dst + i) = o;
}

// ---------- cos/sin tables ----------
__global__ void tab_k(const float* __restrict__ freqs, float* __restrict__ ctab,
                      float* __restrict__ stab){
  int i = blockIdx.x * 256 + threadIdx.x;
  float f = freqs[i];
  ctab[i] = cosf(f);
  stab[i] = sinf(f);
}

// ============ 256x128-tile 2-phase/K-tile GEMM, 100% grid fill ============
// C[i][j] = sum_k A[i][k]*B[j][k], BK=64, 32 K-tiles, 8 waves (2M x 4N).
// LDS: 2 slots x 3 halves (A0,A1,B0) x [128][64] bf16 = 96 KB, XOR swizzle.
// ph1 {rd A0,B0 | stg A0',B0'} MMQ(lo) vmcnt(4); ph2 {rd A1 | stg A1'}
// MMQ(hi) vmcnt(2). Every half lands >=2 phases before read; never drain.
#define SB __builtin_amdgcn_sched_barrier(0)
#define BAR __builtin_amdgcn_s_barrier()
#define VM(n) asm volatile("s_waitcnt vmcnt(" #n ")" ::: "memory")

#define RD_A8(slotb, half) do { _Pragma("unroll") \
  for (int i = 0; i < 4; i++){ _Pragma("unroll") \
    for (int ks = 0; ks < 2; ks++) \
      a[i][ks] = *(const short8*)(L + (slotb) + (half)*8192 + abase + i*2048 + kg[ks]); } } while(0)

#define RD_B8(slotb) do { _Pragma("unroll") \
  for (int n = 0; n < 2; n++){ _Pragma("unroll") \
    for (int ks = 0; ks < 2; ks++) \
      b[n][ks] = *(const short8*)(L + (slotb) + 16384 + bbase + n*4096 + kg[ks]); } } while(0)

#define MMQ8(X) do { __builtin_amdgcn_s_setprio(1); _Pragma("unroll") \
  for (int i = 0; i < 4; i++){ _Pragma("unroll") \
    for (int n = 0; n < 2; n++){ _Pragma("unroll") \
      for (int ks = 0; ks < 2; ks++) \
        acc[(X)*4+i][n] = __builtin_amdgcn_mfma_f32_16x16x32_bf16( \
            a[i][ks], b[n][ks], acc[(X)*4+i][n], 0, 0, 0); } } \
  __builtin_amdgcn_s_setprio(0); } while(0)

template<int EPI>   // 1: QKV (z: 0=Q,1=K,2=V^T), 0: f32 out
__global__ __launch_bounds__(512, 2) void gemm8_k(
    const unsigned short* __restrict__ A,
    const unsigned short* __restrict__ W0,
    const unsigned short* __restrict__ W1,
    const unsigned short* __restrict__ W2,
    unsigned short* __restrict__ O0,
    unsigned short* __restrict__ O1,
    unsigned short* __restrict__ O2,
    float* __restrict__ Of)
{
  __shared__ __align__(16) unsigned short L[2 * 3 * 8192];   // 96 KiB
  const int tid = threadIdx.x;
  const int l = tid & 63, lg = l >> 4, lr = l & 15;
  const int w = tid >> 6, wm = w >> 2, wn = w & 3;
  const int m0 = blockIdx.x * 256, n0 = blockIdx.y * 128;
  const int z = (EPI == 1) ? blockIdx.z : 0;
  const unsigned short* Bop = (EPI == 1) ? (z == 0 ? W0 : (z == 1 ? W1 : W2)) : W0;

  f32x4 acc[8][2];
  #pragma unroll
  for (int i = 0; i < 8; i++)
    #pragma unroll
    for (int j = 0; j < 2; j++)
      acc[i][j] = f32x4{0.f, 0.f, 0.f, 0.f};

  // staging: linear LDS dest, pre-swizzled global source (granule^row&7)
  const int gsw = (((tid & 7) ^ ((tid >> 3) & 7)) * 8);
  const unsigned short* gA = A   + (size_t)(m0 + (tid >> 3)) * HID + gsw;
  const unsigned short* gB = Bop + (size_t)(n0 + (tid >> 3)) * HID + gsw;
  const size_t HIN = (size_t)64  * HID;   // second 64 rows of a half
  const size_t HB  = (size_t)128 * HID;   // A1 base (+128 rows)

  const int abase = (wm * 16 + lr) * 64;
  const int bbase = (wn * 16 + lr) * 64;
  int kg[2];
  kg[0] = ((lg)     ^ (lr & 7)) * 8;
  kg[1] = ((4 + lg) ^ (lr & 7)) * 8;

  #define STG(gsrc, tile, ldst) do { \
    const unsigned short* _s = (gsrc) + (size_t)(tile) * 64; \
    g2lds16(_s,       (ldst) + tid * 8); \
    g2lds16(_s + HIN, (ldst) + 4096 + tid * 8); } while(0)

  short8 a[4][2], b[2][2];

  // prologue: tile0 (A0,A1,B0) -> slot0, drain
  STG(gA,      0, L);
  STG(gA + HB, 0, L + 8192);
  STG(gB,      0, L + 16384);
  VM(0); SB; BAR;

  // PAIR(t even->slot0 stages t+1->slot1; t+1->slot1 stages t+2->slot0)
  #define PH1(sl, osl, tn) do { \
    RD_A8(sl, 0); RD_B8(sl); \
    STG(gA, tn, L + (osl)); STG(gB, tn, L + (osl) + 16384); \
    BAR; MMQ8(0); VM(4); SB; BAR; } while(0)
  #define PH2(sl, osl, tn) do { \
    RD_A8(sl, 1); \
    STG(gA + HB, tn, L + (osl) + 8192); \
    BAR; MMQ8(1); VM(2); SB; BAR; } while(0)

  for (int it = 0; it < 15; ++it){
    const int t1 = 2 * it + 1, t2 = 2 * it + 2;
    PH1(0, 24576, t1); PH2(0, 24576, t1);         // tile 2it   (slot0)
    PH1(24576, 0, t2); PH2(24576, 0, t2);         // tile 2it+1 (slot1)
  }
  // tile 30 (slot0), stages 31
  PH1(0, 24576, 31); PH2(0, 24576, 31);
  // tile 31 (slot1), no staging, drain at ph1-end
  RD_A8(24576, 0); RD_B8(24576);
  BAR; MMQ8(0); VM(0); SB; BAR;
  RD_A8(24576, 1);
  BAR; MMQ8(1);
  #undef PH1
  #undef PH2
  #undef STG

  // epilogue
  #pragma unroll
  for (int mf = 0; mf < 8; mf++)
    #pragma unroll
    for (int nf = 0; nf < 2; nf++){
      const int j = n0 + nf * 64 + wn * 16 + lr;
      const int i0 = m0 + mf * 32 + wm * 16 + lg * 4;
      if (EPI == 0){
        #pragma unroll
        for (int r = 0; r < 4; r++)
          Of[(size_t)(i0 + r) * HID + j] = acc[mf][nf][r];
      } else if (z == 2){
        const int b = i0 >> 11, s = i0 & 2047, h = j >> 7, d = j & 127;
        us4 v;
        #pragma unroll
        for (int r = 0; r < 4; r++) v[r] = f2bf(acc[mf][nf][r]);
        *(us4*)(O2 + ((size_t)(b * H_ + h) * D_ + d) * S_ + s) = v;
      } else {
        unsigned short* O = z ? O1 : O0;
        const int h = j >> 7, d = j & 127;
        #pragma unroll
        for (int r = 0; r < 4; r++){
          const int i = i0 + r;
          const int b = i >> 11, s = i & 2047;
          O[((size_t)(b * H_ + h) * S_ + s) * D_ + d] = f2bf(acc[mf][nf][r]);
        }
      }
    }
}

// ---------- in-place RoPE on Q and K ----------
__global__ void rope_k(unsigned short* __restrict__ Q, unsigned short* __restrict__ K,
                       const float* __restrict__ ctab, const float* __restrict__ stab){
  int idx = blockIdx.x * 256 + threadIdx.x;
  unsigned short* P = (idx >= (1 << 20)) ? K : Q;
  int e  = idx & ((1 << 20) - 1);
  int g  = e & 15;
  int s  = (e >> 4) & 2047;
  int bh = e >> 15;
  int d0 = g * 4;
  size_t base = ((size_t)bh * S_ + s) * D_;
  us4 qa = *(us4*)(P + base + d0);
  us4 qb = *(us4*)(P + base + d0 + 64);
  fl4 ca = *(const fl4*)(ctab + s * D_ + d0);
  fl4 sa = *(const fl4*)(stab + s * D_ + d0);
  fl4 cb = *(const fl4*)(ctab + s * D_ + d0 + 64);
  fl4 sb = *(const fl4*)(stab + s * D_ + d0 + 64);
  us4 oa, ob;
  #pragma unroll
  for (int t = 0; t < 4; t++){
    float xa = bf2f(qa[t]), xb = bf2f(qb[t]);
    oa[t] = f2bf(xa * ca[t] - xb * sa[t]);
    ob[t] = f2bf(xb * cb[t] + xa * sb[t]);
  }
  *(us4*)(P + base + d0)      = oa;
  *(us4*)(P + base + d0 + 64) = ob;
}

// ---------- flash attention (R8-proven): 4 waves, KVBLK=64, dbuf g2lds ----------
__global__ __launch_bounds__(256) void attn_k(
    const unsigned short* __restrict__ Q,
    const unsigned short* __restrict__ Kg,
    const unsigned short* __restrict__ Vt,
    const float* __restrict__ mask,
    const float* __restrict__ alibi,
    unsigned short* __restrict__ Ctx)
{
  __shared__ __align__(16) unsigned short Kl[2][64 * 128];
  __shared__ __align__(16) unsigned short Vl[2][128 * 64];
  const int tid = threadIdx.x;
  const int l = tid & 63, lg = l >> 4, lr = l & 15;
  const int w = tid >> 6;
  const int bh = blockIdx.y, b = bh >> 4, h = bh & 15;
  const int q0 = blockIdx.x * 64 + w * 16;
  const size_t hb = (size_t)bh * S_ * D_;
  const float* mrow = mask + (size_t)(q0 + lr) * S_;
  const float* al = alibi + h * S_;
  const int sidx = (l & 48) + ((l & 48) >> 2);
  const float SCL2E = 0.08838834764831845f * 1.4426950408889634f;
  const float L2E = 1.4426950408889634f;

  const int kswz = (((tid & 15) ^ ((tid >> 4) & 7)) * 8);
  const unsigned short* gK = Kg + hb + (size_t)(tid >> 4) * D_ + kswz;
  const int vswz = (((tid & 7) ^ ((tid >> 3) & 7)) * 8);
  const unsigned short* gV = Vt + hb + (size_t)(tid >> 3) * S_ + vswz;

  #define ASTAGE(buf, kv)  do {                                            \
    g2lds16(gK + (size_t)((kv))      * D_, Kl[buf] + tid * 8);             \
    g2lds16(gK + (size_t)((kv) + 16) * D_, Kl[buf] + 2048 + tid * 8);      \
    g2lds16(gK + (size_t)((kv) + 32) * D_, Kl[buf] + 4096 + tid * 8);      \
    g2lds16(gK + (size_t)((kv) + 48) * D_, Kl[buf] + 6144 + tid * 8);      \
    g2lds16(gV + (kv),                     Vl[buf] + tid * 8);             \
    g2lds16(gV + 32 * S_ + (kv),           Vl[buf] + 2048 + tid * 8);      \
    g2lds16(gV + 64 * S_ + (kv),           Vl[buf] + 4096 + tid * 8);      \
    g2lds16(gV + 96 * S_ + (kv),           Vl[buf] + 6144 + tid * 8);      \
  } while (0)

  int koff[4];
  #pragma unroll
  for (int c = 0; c < 4; c++) koff[c] = ((c * 4 + lg) ^ (lr & 7)) * 8;
  const int vo0 = (lg ^ (lr & 7)) * 8, vo1 = ((4 + lg) ^ (lr & 7)) * 8;

  short8 qf[4];
  #pragma unroll
  for (int c = 0; c < 4; c++)
    qf[c] = *(const short8*)(Q + hb + (size_t)(q0 + lr) * D_ + c * 32 + lg * 8);

  f32x4 acc[8];
  #pragma unroll
  for (int c = 0; c < 8; c++) acc[c] = f32x4{0.f, 0.f, 0.f, 0.f};
  float mr = -1e30f, lsum = 0.f;

  ASTAGE(0, 0);
  __syncthreads();
  int cur = 0;

  for (int t = 0; t < 32; t++){
    const int kv0 = t * 64;
    if (t < 31) ASTAGE(cur ^ 1, kv0 + 64);

    fl4 mk[4], aa[4];
    #pragma unroll
    for (int g = 0; g < 4; g++){
      mk[g] = *(const fl4*)(mrow + kv0 + g * 16 + 4 * lg);
      aa[g] = *(const fl4*)(al  + kv0 + g * 16 + 4 * lg);
    }

    f32x4 sg[4];
    #pragma unroll
    for (int g = 0; g < 4; g++) sg[g] = f32x4{0.f, 0.f, 0.f, 0.f};
    #pragma unroll
    for (int g = 0; g < 4; g++){
      const int row = g * 16 + lr;
      #pragma unroll
      for (int c = 0; c < 4; c++){
        short8 kf = *(const short8*)(Kl[cur] + row * 128 + koff[c]);
        sg[g] = __builtin_amdgcn_mfma_f32_16x16x32_bf16(kf, qf[c], sg[g], 0, 0, 0);
      }
    }

    float x[4][4];
    #pragma unroll
    for (int g = 0; g < 4; g++)
      #pragma unroll
      for (int r = 0; r < 4; r++)
        x[g][r] = fmaf(sg[g][r], SCL2E, (mk[g][r] + aa[g][r]) * L2E);

    float mx = -1e30f;
    #pragma unroll
    for (int g = 0; g < 4; g++)
      #pragma unroll
      for (int r = 0; r < 4; r++) mx = fmaxf(mx, x[g][r]);

    float p[4][4], ps = 0.f;
    if (__all(mx <= mr + 8.f)){
      #pragma unroll
      for (int g = 0; g < 4; g++)
        #pragma unroll
        for (int r = 0; r < 4; r++){
          p[g][r] = exp2f(x[g][r] - mr);
          ps += p[g][r];
        }
      ps += __shfl_xor(ps, 16);
      ps += __shfl_xor(ps, 32);
      lsum += ps;
    } else {
      mx = fmaxf(mx, __shfl_xor(mx, 16));
      mx = fmaxf(mx, __shfl_xor(mx, 32));
      float mnew = fmaxf(mr, mx);
      float alpha = exp2f(mr - mnew);
      #pragma unroll
      for (int g = 0; g < 4; g++)
        #pragma unroll
        for (int r = 0; r < 4; r++){
          p[g][r] = exp2f(x[g][r] - mnew);
          ps += p[g][r];
        }
      ps += __shfl_xor(ps, 16);
      ps += __shfl_xor(ps, 32);
      lsum = lsum * alpha + ps;
      mr = mnew;
      float ar[4];
      #pragma unroll
      for (int r = 0; r < 4; r++) ar[r] = __shfl(alpha, sidx + r);
      #pragma unroll
      for (int c = 0; c < 8; c++)
        #pragma unroll
        for (int r = 0; r < 4; r++) acc[c][r] *= ar[r];
    }

    int pk0[4], pk1[4];
    #pragma unroll
    for (int r = 0; r < 4; r++){
      pk0[r] = cvtpk(p[0][r], p[1][r]);
      pk1[r] = cvtpk(p[2][r], p[3][r]);
    }

    const int srcb = lr + ((lg & 1) << 5);
    short8 af0, af1;
    #pragma unroll
    for (int j = 0; j < 8; j++){
      int w0 = __shfl(pk0[j & 3], srcb + ((j >> 2) << 4));
      int w1 = __shfl(pk1[j & 3], srcb + ((j >> 2) << 4));
      af0[j] = (short)((l & 32) ? ((unsigned)w0 >> 16) : ((unsigned)w0 & 0xffffu));
      af1[j] = (short)((l & 32) ? ((unsigned)w1 >> 16) : ((unsigned)w1 & 0xffffu));
    }

    #pragma unroll
    for (int c = 0; c < 8; c++){
      const int d0 = c * 16 + lr;
      short8 vf0 = *(const short8*)(Vl[cur] + d0 * 64 + vo0);
      short8 vf1 = *(const short8*)(Vl[cur] + d0 * 64 + vo1);
      acc[c] = __builtin_amdgcn_mfma_f32_16x16x32_bf16(af0, vf0, acc[c], 0, 0, 0);
      acc[c] = __builtin_amdgcn_mfma_f32_16x16x32_bf16(af1, vf1, acc[c], 0, 0, 0);
    }

    __syncthreads();
    cur ^= 1;
  }
  #undef ASTAGE

  float inv = 1.f / lsum;
  float ir[4];
  #pragma unroll
  for (int r = 0; r < 4; r++) ir[r] = __shfl(inv, sidx + r);
  #pragma unroll
  for (int r = 0; r < 4; r++){
    const int qg = q0 + 4 * lg + r;
    const size_t ob = ((size_t)(b * S_ + qg) * H_ + h) * D_;
    #pragma unroll
    for (int c = 0; c < 8; c++)
      Ctx[ob + c * 16 + lr] = f2bf(acc[c][r] * ir[r]);
  }
}

extern "C" void kernel_launch(void* const* d_in, const int* in_sizes, int n_in,
                              void* d_out, int out_size, void* d_ws, size_t ws_size,
                              hipStream_t stream){
  const float* x     = (const float*)d_in[0];
  const float* mask  = (const float*)d_in[1];
  const float* alibi = (const float*)d_in[2];
  const float* freqs = (const float*)d_in[3];
  const float* Wq    = (const float*)d_in[4];
  const float* Wk    = (const float*)d_in[5];
  const float* Wv    = (const float*)d_in[6];
  const float* Wo    = (const float*)d_in[7];
  float* out = (float*)d_out;

  unsigned short* ws  = (unsigned short*)d_ws;
  unsigned short* xb  = ws;
  unsigned short* wqb = ws + 8388608;
  unsigned short* wkb = ws + 12582912;
  unsigned short* wvb = ws + 16777216;
  unsigned short* wob = ws + 20971520;
  unsigned short* Qb  = ws + 25165824;
  unsigned short* Kb  = ws + 33554432;
  unsigned short* Vb  = ws + 41943040;         // V^T [B,H,D,S]
  unsigned short* ctx = xb;
  float* ctab = (float*)(ws + 50331648);
  float* stab = ctab + 262144;

  cvt_k<<<8192, 256, 0, stream>>>(x,  xb);
  cvt_k<<<4096, 256, 0, stream>>>(Wq, wqb);
  cvt_k<<<4096, 256, 0, stream>>>(Wk, wkb);
  cvt_k<<<4096, 256, 0, stream>>>(Wv, wvb);
  cvt_k<<<4096, 256, 0, stream>>>(Wo, wob);
  tab_k<<<1024, 256, 0, stream>>>(freqs, ctab, stab);

  gemm8_k<1><<<dim3(16, 16, 3), 512, 0, stream>>>(xb, wqb, wkb, wvb,
                                                  Qb, Kb, Vb, nullptr);
  rope_k<<<8192, 256, 0, stream>>>(Qb, Kb, ctab, stab);
  attn_k<<<dim3(32, 32), 256, 0, stream>>>(Qb, Kb, Vb, mask, alibi, ctx);
  gemm8_k<0><<<dim3(16, 16, 1), 512, 0, stream>>>(ctx, wob, nullptr, nullptr,
                                                  nullptr, nullptr, nullptr, out);
}

// Round 11
// 463.436 us; speedup vs baseline: 1.2067x; 1.0763x over previous
//
#include <hip/hip_runtime.h>
#include <math.h>

typedef __attribute__((ext_vector_type(8))) short short8;
typedef __attribute__((ext_vector_type(4))) float f32x4;
typedef __attribute__((ext_vector_type(4))) unsigned short us4;
typedef __attribute__((ext_vector_type(4))) float fl4;

#define B_ 2
#define S_ 2048
#define H_ 16
#define D_ 128
#define HID 2048

__device__ __forceinline__ unsigned short f2bf(float f){
  unsigned u = __builtin_bit_cast(unsigned, f);
  u += 0x7fffu + ((u >> 16) & 1u);
  return (unsigned short)(u >> 16);
}
__device__ __forceinline__ float bf2f(unsigned short u){
  unsigned x = ((unsigned)u) << 16;
  return __builtin_bit_cast(float, x);
}
__device__ __forceinline__ int cvtpk(float lo, float hi){
  int r; asm("v_cvt_pk_bf16_f32 %0, %1, %2" : "=v"(r) : "v"(lo), "v"(hi)); return r;
}

// async global -> LDS, 16 bytes per lane (dest linear: base + lane*16)
__device__ __forceinline__ void g2lds16(const unsigned short* g, unsigned short* l){
  __builtin_amdgcn_global_load_lds(
      (const __attribute__((address_space(1))) unsigned int*)g,
      (__attribute__((address_space(3))) unsigned int*)l, 16, 0, 0);
}

// ---------- f32 -> bf16 convert (x) ----------
__global__ void cvt_k(const float* __restrict__ src, unsigned short* __restrict__ dst){
  int i = (blockIdx.x * 256 + threadIdx.x) * 4;
  fl4 v = *(const fl4*)(src + i);
  us4 o;
  #pragma unroll
  for (int t = 0; t < 4; t++) o[t] = f2bf(v[t]);
  *(us4*)(dst + i) = o;
}

// ---------- merged weight convert: Wq,Wk,Wv,Wo -> contiguous bf16 ----------
__global__ void cvtw_k(const float* __restrict__ Wq, const float* __restrict__ Wk,
                       const float* __restrict__ Wv, const float* __restrict__ Wo,
                       unsigned short* __restrict__ dst){
  int bi = blockIdx.x;                 // 0..16383
  int which = bi >> 12;
  const float* src = which == 0 ? Wq : (which == 1 ? Wk : (which == 2 ? Wv : Wo));
  int local = ((bi & 4095) * 256 + threadIdx.x) * 4;
  fl4 v = *(const fl4*)(src + local);
  us4 o;
  #pragma unroll
  for (int t = 0; t < 4; t++) o[t] = f2bf(v[t]);
  *(us4*)(dst + which * 4194304 + local) = o;
}

// ---------- cos/sin tables ----------
__global__ void tab_k(const float* __restrict__ freqs, float* __restrict__ ctab,
                      float* __restrict__ stab){
  int i = blockIdx.x * 256 + threadIdx.x;
  float f = freqs[i];
  ctab[i] = cosf(f);
  stab[i] = sinf(f);
}

// ============ 256x128-tile 2-phase/K-tile GEMM (R10-proven schedule) ============
// EPI==1 z in {0,1}: fused f32 RoPE in epilogue (thread holds the (d,d+64) pair
// as acc[mf][0]/acc[mf][1] since BN=128 spans exactly one head).
#define SB __builtin_amdgcn_sched_barrier(0)
#define BAR __builtin_amdgcn_s_barrier()
#define VM(n) asm volatile("s_waitcnt vmcnt(" #n ")" ::: "memory")

#define RD_A8(slotb, half) do { _Pragma("unroll") \
  for (int i = 0; i < 4; i++){ _Pragma("unroll") \
    for (int ks = 0; ks < 2; ks++) \
      a[i][ks] = *(const short8*)(L + (slotb) + (half)*8192 + abase + i*2048 + kg[ks]); } } while(0)

#define RD_B8(slotb) do { _Pragma("unroll") \
  for (int n = 0; n < 2; n++){ _Pragma("unroll") \
    for (int ks = 0; ks < 2; ks++) \
      b[n][ks] = *(const short8*)(L + (slotb) + 16384 + bbase + n*4096 + kg[ks]); } } while(0)

#define MMQ8(X) do { __builtin_amdgcn_s_setprio(1); _Pragma("unroll") \
  for (int i = 0; i < 4; i++){ _Pragma("unroll") \
    for (int n = 0; n < 2; n++){ _Pragma("unroll") \
      for (int ks = 0; ks < 2; ks++) \
        acc[(X)*4+i][n] = __builtin_amdgcn_mfma_f32_16x16x32_bf16( \
            a[i][ks], b[n][ks], acc[(X)*4+i][n], 0, 0, 0); } } \
  __builtin_amdgcn_s_setprio(0); } while(0)

template<int EPI>   // 1: QKV (z: 0=Q,1=K rope'd, 2=V^T), 0: f32 out
__global__ __launch_bounds__(512, 2) void gemm8_k(
    const unsigned short* __restrict__ A,
    const unsigned short* __restrict__ W0,
    const unsigned short* __restrict__ W1,
    const unsigned short* __restrict__ W2,
    unsigned short* __restrict__ O0,
    unsigned short* __restrict__ O1,
    unsigned short* __restrict__ O2,
    float* __restrict__ Of,
    const float* __restrict__ ctab,
    const float* __restrict__ stab)
{
  __shared__ __align__(16) unsigned short L[2 * 3 * 8192];   // 96 KiB
  const int tid = threadIdx.x;
  const int l = tid & 63, lg = l >> 4, lr = l & 15;
  const int w = tid >> 6, wm = w >> 2, wn = w & 3;
  const int m0 = blockIdx.x * 256, n0 = blockIdx.y * 128;
  const int z = (EPI == 1) ? blockIdx.z : 0;
  const unsigned short* Bop = (EPI == 1) ? (z == 0 ? W0 : (z == 1 ? W1 : W2)) : W0;

  f32x4 acc[8][2];
  #pragma unroll
  for (int i = 0; i < 8; i++)
    #pragma unroll
    for (int j = 0; j < 2; j++)
      acc[i][j] = f32x4{0.f, 0.f, 0.f, 0.f};

  const int gsw = (((tid & 7) ^ ((tid >> 3) & 7)) * 8);
  const unsigned short* gA = A   + (size_t)(m0 + (tid >> 3)) * HID + gsw;
  const unsigned short* gB = Bop + (size_t)(n0 + (tid >> 3)) * HID + gsw;
  const size_t HIN = (size_t)64  * HID;
  const size_t HB  = (size_t)128 * HID;

  const int abase = (wm * 16 + lr) * 64;
  const int bbase = (wn * 16 + lr) * 64;
  int kg[2];
  kg[0] = ((lg)     ^ (lr & 7)) * 8;
  kg[1] = ((4 + lg) ^ (lr & 7)) * 8;

  #define STG(gsrc, tile, ldst) do { \
    const unsigned short* _s = (gsrc) + (size_t)(tile) * 64; \
    g2lds16(_s,       (ldst) + tid * 8); \
    g2lds16(_s + HIN, (ldst) + 4096 + tid * 8); } while(0)

  short8 a[4][2], b[2][2];

  STG(gA,      0, L);
  STG(gA + HB, 0, L + 8192);
  STG(gB,      0, L + 16384);
  VM(0); SB; BAR;

  #define PH1(sl, osl, tn) do { \
    RD_A8(sl, 0); RD_B8(sl); \
    STG(gA, tn, L + (osl)); STG(gB, tn, L + (osl) + 16384); \
    BAR; MMQ8(0); VM(4); SB; BAR; } while(0)
  #define PH2(sl, osl, tn) do { \
    RD_A8(sl, 1); \
    STG(gA + HB, tn, L + (osl) + 8192); \
    BAR; MMQ8(1); VM(2); SB; BAR; } while(0)

  for (int it = 0; it < 15; ++it){
    const int t1 = 2 * it + 1, t2 = 2 * it + 2;
    PH1(0, 24576, t1); PH2(0, 24576, t1);
    PH1(24576, 0, t2); PH2(24576, 0, t2);
  }
  PH1(0, 24576, 31); PH2(0, 24576, 31);
  RD_A8(24576, 0); RD_B8(24576);
  BAR; MMQ8(0); VM(0); SB; BAR;
  RD_A8(24576, 1);
  BAR; MMQ8(1);
  #undef PH1
  #undef PH2
  #undef STG

  // ---------------- epilogue ----------------
  if (EPI == 0){
    #pragma unroll
    for (int mf = 0; mf < 8; mf++)
      #pragma unroll
      for (int nf = 0; nf < 2; nf++){
        const int j = n0 + nf * 64 + wn * 16 + lr;
        const int i0 = m0 + mf * 32 + wm * 16 + lg * 4;
        #pragma unroll
        for (int r = 0; r < 4; r++)
          Of[(size_t)(i0 + r) * HID + j] = acc[mf][nf][r];
      }
  } else if (z == 2){
    #pragma unroll
    for (int mf = 0; mf < 8; mf++)
      #pragma unroll
      for (int nf = 0; nf < 2; nf++){
        const int j = n0 + nf * 64 + wn * 16 + lr;
        const int i0 = m0 + mf * 32 + wm * 16 + lg * 4;
        const int b = i0 >> 11, s = i0 & 2047, h = j >> 7, d = j & 127;
        us4 v;
        #pragma unroll
        for (int r = 0; r < 4; r++) v[r] = f2bf(acc[mf][nf][r]);
        *(us4*)(O2 + ((size_t)(b * H_ + h) * D_ + d) * S_ + s) = v;
      }
  } else {
    // Q/K with fused f32 RoPE: dlo = wn*16+lr in [0,64), pair = (dlo, dlo+64)
    unsigned short* O = z ? O1 : O0;
    const int h = n0 >> 7;
    const int dlo = wn * 16 + lr;
    #pragma unroll
    for (int mf = 0; mf < 8; mf++){
      #pragma unroll
      for (int r = 0; r < 4; r++){
        const int i = m0 + mf * 32 + wm * 16 + lg * 4 + r;
        const int b = i >> 11, s = i & 2047;
        const float xa = acc[mf][0][r], xb = acc[mf][1][r];
        const float cl = ctab[s * D_ + dlo],      sl = stab[s * D_ + dlo];
        const float ch = ctab[s * D_ + dlo + 64], sh = stab[s * D_ + dlo + 64];
        const size_t base = ((size_t)(b * H_ + h) * S_ + s) * D_;
        O[base + dlo]      = f2bf(xa * cl - xb * sl);
        O[base + dlo + 64] = f2bf(xb * ch + xa * sh);
      }
    }
  }
}

// ---------- flash attention (R8-proven) + XCD-grouped grid ----------
__global__ __launch_bounds__(256) void attn_k(
    const unsigned short* __restrict__ Q,
    const unsigned short* __restrict__ Kg,
    const unsigned short* __restrict__ Vt,
    const float* __restrict__ mask,
    const float* __restrict__ alibi,
    unsigned short* __restrict__ Ctx)
{
  __shared__ __align__(16) unsigned short Kl[2][64 * 128];
  __shared__ __align__(16) unsigned short Vl[2][128 * 64];
  const int tid = threadIdx.x;
  const int l = tid & 63, lg = l >> 4, lr = l & 15;
  const int w = tid >> 6;
  // XCD-grouped: each XCD owns 4 consecutive bh -> K/V L2-resident
  const int f = blockIdx.x;
  const int g0 = (f & 7) * 128 + (f >> 3);
  const int bh = g0 >> 5, qx = g0 & 31;
  const int b = bh >> 4, h = bh & 15;
  const int q0 = qx * 64 + w * 16;
  const size_t hb = (size_t)bh * S_ * D_;
  const float* mrow = mask + (size_t)(q0 + lr) * S_;
  const float* al = alibi + h * S_;
  const int sidx = (l & 48) + ((l & 48) >> 2);
  const float SCL2E = 0.08838834764831845f * 1.4426950408889634f;
  const float L2E = 1.4426950408889634f;

  const int kswz = (((tid & 15) ^ ((tid >> 4) & 7)) * 8);
  const unsigned short* gK = Kg + hb + (size_t)(tid >> 4) * D_ + kswz;
  const int vswz = (((tid & 7) ^ ((tid >> 3) & 7)) * 8);
  const unsigned short* gV = Vt + hb + (size_t)(tid >> 3) * S_ + vswz;

  #define ASTAGE(buf, kv)  do {                                            \
    g2lds16(gK + (size_t)((kv))      * D_, Kl[buf] + tid * 8);             \
    g2lds16(gK + (size_t)((kv) + 16) * D_, Kl[buf] + 2048 + tid * 8);      \
    g2lds16(gK + (size_t)((kv) + 32) * D_, Kl[buf] + 4096 + tid * 8);      \
    g2lds16(gK + (size_t)((kv) + 48) * D_, Kl[buf] + 6144 + tid * 8);      \
    g2lds16(gV + (kv),                     Vl[buf] + tid * 8);             \
    g2lds16(gV + 32 * S_ + (kv),           Vl[buf] + 2048 + tid * 8);      \
    g2lds16(gV + 64 * S_ + (kv),           Vl[buf] + 4096 + tid * 8);      \
    g2lds16(gV + 96 * S_ + (kv),           Vl[buf] + 6144 + tid * 8);      \
  } while (0)

  int koff[4];
  #pragma unroll
  for (int c = 0; c < 4; c++) koff[c] = ((c * 4 + lg) ^ (lr & 7)) * 8;
  const int vo0 = (lg ^ (lr & 7)) * 8, vo1 = ((4 + lg) ^ (lr & 7)) * 8;

  short8 qf[4];
  #pragma unroll
  for (int c = 0; c < 4; c++)
    qf[c] = *(const short8*)(Q + hb + (size_t)(q0 + lr) * D_ + c * 32 + lg * 8);

  f32x4 acc[8];
  #pragma unroll
  for (int c = 0; c < 8; c++) acc[c] = f32x4{0.f, 0.f, 0.f, 0.f};
  float mr = -1e30f, lsum = 0.f;

  ASTAGE(0, 0);
  __syncthreads();
  int cur = 0;

  for (int t = 0; t < 32; t++){
    const int kv0 = t * 64;
    if (t < 31) ASTAGE(cur ^ 1, kv0 + 64);

    fl4 mk[4], aa[4];
    #pragma unroll
    for (int g = 0; g < 4; g++){
      mk[g] = *(const fl4*)(mrow + kv0 + g * 16 + 4 * lg);
      aa[g] = *(const fl4*)(al  + kv0 + g * 16 + 4 * lg);
    }

    f32x4 sg[4];
    #pragma unroll
    for (int g = 0; g < 4; g++) sg[g] = f32x4{0.f, 0.f, 0.f, 0.f};
    #pragma unroll
    for (int g = 0; g < 4; g++){
      const int row = g * 16 + lr;
      #pragma unroll
      for (int c = 0; c < 4; c++){
        short8 kf = *(const short8*)(Kl[cur] + row * 128 + koff[c]);
        sg[g] = __builtin_amdgcn_mfma_f32_16x16x32_bf16(kf, qf[c], sg[g], 0, 0, 0);
      }
    }

    float x[4][4];
    #pragma unroll
    for (int g = 0; g < 4; g++)
      #pragma unroll
      for (int r = 0; r < 4; r++)
        x[g][r] = fmaf(sg[g][r], SCL2E, (mk[g][r] + aa[g][r]) * L2E);

    float mx = -1e30f;
    #pragma unroll
    for (int g = 0; g < 4; g++)
      #pragma unroll
      for (int r = 0; r < 4; r++) mx = fmaxf(mx, x[g][r]);

    float p[4][4], ps = 0.f;
    if (__all(mx <= mr + 8.f)){
      #pragma unroll
      for (int g = 0; g < 4; g++)
        #pragma unroll
        for (int r = 0; r < 4; r++){
          p[g][r] = exp2f(x[g][r] - mr);
          ps += p[g][r];
        }
      ps += __shfl_xor(ps, 16);
      ps += __shfl_xor(ps, 32);
      lsum += ps;
    } else {
      mx = fmaxf(mx, __shfl_xor(mx, 16));
      mx = fmaxf(mx, __shfl_xor(mx, 32));
      float mnew = fmaxf(mr, mx);
      float alpha = exp2f(mr - mnew);
      #pragma unroll
      for (int g = 0; g < 4; g++)
        #pragma unroll
        for (int r = 0; r < 4; r++){
          p[g][r] = exp2f(x[g][r] - mnew);
          ps += p[g][r];
        }
      ps += __shfl_xor(ps, 16);
      ps += __shfl_xor(ps, 32);
      lsum = lsum * alpha + ps;
      mr = mnew;
      float ar[4];
      #pragma unroll
      for (int r = 0; r < 4; r++) ar[r] = __shfl(alpha, sidx + r);
      #pragma unroll
      for (int c = 0; c < 8; c++)
        #pragma unroll
        for (int r = 0; r < 4; r++) acc[c][r] *= ar[r];
    }

    int pk0[4], pk1[4];
    #pragma unroll
    for (int r = 0; r < 4; r++){
      pk0[r] = cvtpk(p[0][r], p[1][r]);
      pk1[r] = cvtpk(p[2][r], p[3][r]);
    }

    const int srcb = lr + ((lg & 1) << 5);
    short8 af0, af1;
    #pragma unroll
    for (int j = 0; j < 8; j++){
      int w0 = __shfl(pk0[j & 3], srcb + ((j >> 2) << 4));
      int w1 = __shfl(pk1[j & 3], srcb + ((j >> 2) << 4));
      af0[j] = (short)((l & 32) ? ((unsigned)w0 >> 16) : ((unsigned)w0 & 0xffffu));
      af1[j] = (short)((l & 32) ? ((unsigned)w1 >> 16) : ((unsigned)w1 & 0xffffu));
    }

    #pragma unroll
    for (int c = 0; c < 8; c++){
      const int d0 = c * 16 + lr;
      short8 vf0 = *(const short8*)(Vl[cur] + d0 * 64 + vo0);
      short8 vf1 = *(const short8*)(Vl[cur] + d0 * 64 + vo1);
      acc[c] = __builtin_amdgcn_mfma_f32_16x16x32_bf16(af0, vf0, acc[c], 0, 0, 0);
      acc[c] = __builtin_amdgcn_mfma_f32_16x16x32_bf16(af1, vf1, acc[c], 0, 0, 0);
    }

    __syncthreads();
    cur ^= 1;
  }
  #undef ASTAGE

  float inv = 1.f / lsum;
  float ir[4];
  #pragma unroll
  for (int r = 0; r < 4; r++) ir[r] = __shfl(inv, sidx + r);
  #pragma unroll
  for (int r = 0; r < 4; r++){
    const int qg = q0 + 4 * lg + r;
    const size_t ob = ((size_t)(b * S_ + qg) * H_ + h) * D_;
    #pragma unroll
    for (int c = 0; c < 8; c++)
      Ctx[ob + c * 16 + lr] = f2bf(acc[c][r] * ir[r]);
  }
}

extern "C" void kernel_launch(void* const* d_in, const int* in_sizes, int n_in,
                              void* d_out, int out_size, void* d_ws, size_t ws_size,
                              hipStream_t stream){
  const float* x     = (const float*)d_in[0];
  const float* mask  = (const float*)d_in[1];
  const float* alibi = (const float*)d_in[2];
  const float* freqs = (const float*)d_in[3];
  const float* Wq    = (const float*)d_in[4];
  const float* Wk    = (const float*)d_in[5];
  const float* Wv    = (const float*)d_in[6];
  const float* Wo    = (const float*)d_in[7];
  float* out = (float*)d_out;

  unsigned short* ws  = (unsigned short*)d_ws;
  unsigned short* xb  = ws;
  unsigned short* wqb = ws + 8388608;          // wqb..wob contiguous
  unsigned short* wkb = ws + 12582912;
  unsigned short* wvb = ws + 16777216;
  unsigned short* wob = ws + 20971520;
  unsigned short* Qb  = ws + 25165824;
  unsigned short* Kb  = ws + 33554432;
  unsigned short* Vb  = ws + 41943040;         // V^T [B,H,D,S]
  unsigned short* ctx = xb;
  float* ctab = (float*)(ws + 50331648);
  float* stab = ctab + 262144;

  tab_k<<<1024, 256, 0, stream>>>(freqs, ctab, stab);
  cvt_k<<<8192, 256, 0, stream>>>(x, xb);
  cvtw_k<<<16384, 256, 0, stream>>>(Wq, Wk, Wv, Wo, wqb);

  gemm8_k<1><<<dim3(16, 16, 3), 512, 0, stream>>>(xb, wqb, wkb, wvb,
                                                  Qb, Kb, Vb, nullptr, ctab, stab);
  attn_k<<<1024, 256, 0, stream>>>(Qb, Kb, Vb, mask, alibi, ctx);
  gemm8_k<0><<<dim3(16, 16, 1), 512, 0, stream>>>(ctx, wob, nullptr, nullptr,
                                                  nullptr, nullptr, nullptr, out,
                                                  nullptr, nullptr);
}